// Round 6
// baseline (245.483 us; speedup 1.0000x reference)
//
#include <hip/hip_runtime.h>
#include <hip/hip_bf16.h>

// X: [16, 2048, 128] f32, Y: [16, 2048, 128] f32 -> out: [16, 2048, 2048] f32
// out[b,n,m] = 1/(1+sqrt(max(||x||^2+||y||^2-2 x.y, 1e-7)))
#define Bb 16
#define Nn 2048
#define Mm 2048
#define Dd 128
#define TN 64                                   // tile rows (n)
#define TM 32                                   // tile cols (m)
#define KH 64                                   // K half staged per pass
#define NWG (Bb * (Nn / TN) * (Mm / TM))        // 32768

typedef __attribute__((ext_vector_type(4))) float          f32x4;
typedef __attribute__((ext_vector_type(8))) unsigned short u16x8;
typedef __attribute__((ext_vector_type(8))) __bf16         bf16x8;

__device__ __forceinline__ unsigned short f32_to_bf16_rne(float f) {
  unsigned int u = __builtin_bit_cast(unsigned int, f);
  u += 0x7fffu + ((u >> 16) & 1u);
  return (unsigned short)(u >> 16);
}

// One block (256 thr, 4 waves) = one 64x32 output tile (8 KB).
// LDS = 12.7 KB -> 8 blocks/CU (thread-limited) = 32 waves/CU (max occupancy).
// Live output footprint = 8 x 8KB x 32 CU = 2 MB/XCD (half of L2): stores
// merge cleanly (R0/R5-proven regime) with margin for the input panels.
__global__ __launch_bounds__(256, 8)
void dist_sim_kernel(const float* __restrict__ X, const float* __restrict__ Y,
                     float* __restrict__ out) {
  __shared__ alignas(16) unsigned short Xs[TN * KH];  // 8 KB  (bf16, swizzled)
  __shared__ alignas(16) unsigned short Ys[TM * KH];  // 4 KB
  __shared__ alignas(16) float xsq[TN];
  __shared__ alignas(16) float ysq[TM];

  const int tid = threadIdx.x;

  // Bijective XCD-chunked swizzle (NWG % 8 == 0); bm fastest within a chunk
  // -> one X panel (32 KB) reused across 64 consecutive blocks on one XCD.
  const int wg  = blockIdx.x;
  const int swz = (wg & 7) * (NWG / 8) + (wg >> 3);
  const int bm  = swz & 63;          // 0..63
  const int bn  = (swz >> 6) & 31;   // 0..31
  const int b   = swz >> 11;         // 0..15

  const float* Xb = X + ((size_t)b * Nn + (size_t)bn * TN) * Dd;
  const float* Yb = Y + ((size_t)b * Mm + (size_t)bm * TM) * Dd;

  // Staging map: 8 floats/thread; 8 threads per 64-col half-row.
  const int r8 = tid >> 3;          // 0..31
  const int c0 = (tid & 7) * 8;     // 0..56

  float ssx[2] = {0.f, 0.f};
  float ssy    = 0.f;

  const int lane = tid & 63;
  const int wid  = tid >> 6;           // 0..3
  const int wr   = (wid >> 1) * 32;    // 0 or 32   (n quadrant)
  const int wc   = (wid & 1) * 16;     // 0 or 16   (m half)
  const int fr   = lane & 15;
  const int kg   = lane >> 4;          // 0..3

  f32x4 acc[2];
  acc[0] = (f32x4){0.f, 0.f, 0.f, 0.f};
  acc[1] = (f32x4){0.f, 0.f, 0.f, 0.f};

  #pragma unroll
  for (int half = 0; half < 2; ++half) {
    if (half == 1) __syncthreads();  // half-0 readers done before re-stage

    // ---- stage: global f32 -> LDS bf16 (swizzled), accumulate f32 norms ----
    #pragma unroll
    for (int p = 0; p < 2; ++p) {    // X: 64 rows in 2 passes
      const int row = p * 32 + r8;
      const float* pp = Xb + row * Dd + half * KH + c0;
      f32x4 v0 = *(const f32x4*)(pp);
      f32x4 v1 = *(const f32x4*)(pp + 4);
      u16x8 w;
      float s = 0.f;
      #pragma unroll
      for (int e = 0; e < 4; ++e) {
        s += v0[e] * v0[e] + v1[e] * v1[e];
        w[e]     = f32_to_bf16_rne(v0[e]);
        w[e + 4] = f32_to_bf16_rne(v1[e]);
      }
      ssx[p] += s;
      const int idx = (row * KH + c0) ^ ((row & 7) << 3);  // bank swizzle
      *(u16x8*)&Xs[idx] = w;
    }
    {                                // Y: 32 rows in 1 pass
      const int row = r8;
      const float* pp = Yb + row * Dd + half * KH + c0;
      f32x4 v0 = *(const f32x4*)(pp);
      f32x4 v1 = *(const f32x4*)(pp + 4);
      u16x8 w;
      float s = 0.f;
      #pragma unroll
      for (int e = 0; e < 4; ++e) {
        s += v0[e] * v0[e] + v1[e] * v1[e];
        w[e]     = f32_to_bf16_rne(v0[e]);
        w[e + 4] = f32_to_bf16_rne(v1[e]);
      }
      ssy += s;
      const int idx = (row * KH + c0) ^ ((row & 7) << 3);
      *(u16x8*)&Ys[idx] = w;
    }

    // Publish f32 norms after the final stage pass (8 lanes share a row).
    if (half == 1) {
      #pragma unroll
      for (int p = 0; p < 2; ++p) {
        float sx = ssx[p];
        sx += __shfl_xor(sx, 1);
        sx += __shfl_xor(sx, 2);
        sx += __shfl_xor(sx, 4);
        if ((tid & 7) == 0) xsq[p * 32 + r8] = sx;
      }
      float sy = ssy;
      sy += __shfl_xor(sy, 1);
      sy += __shfl_xor(sy, 2);
      sy += __shfl_xor(sy, 4);
      if ((tid & 7) == 0) ysq[r8] = sy;
    }
    __syncthreads();

    // ---- MFMA over this K-half, swapped operands: D[m-frag][n-frag] --------
    // acc[i] value (lane fr,kg; reg r): n = wr+i*16+fr, m = wc+kg*4+r
    #pragma unroll
    for (int kk = 0; kk < 2; ++kk) {
      bf16x8 a[2], bb;
      #pragma unroll
      for (int i = 0; i < 2; ++i) {
        const int row = wr + i * 16 + fr;
        const int idx = (row * KH + kk * 32 + kg * 8) ^ ((row & 7) << 3);
        a[i] = __builtin_bit_cast(bf16x8, *(const u16x8*)&Xs[idx]);
      }
      {
        const int row = wc + fr;
        const int idx = (row * KH + kk * 32 + kg * 8) ^ ((row & 7) << 3);
        bb = __builtin_bit_cast(bf16x8, *(const u16x8*)&Ys[idx]);
      }
      #pragma unroll
      for (int i = 0; i < 2; ++i)
        acc[i] = __builtin_amdgcn_mfma_f32_16x16x32_bf16(bb, a[i], acc[i], 0, 0, 0);
    }
  }

  // ---- epilogue: d2 -> 1/(1+sqrt(d2)), lane-contiguous f32x4 stores --------
  float xv[2];
  xv[0] = xsq[wr + fr];
  xv[1] = xsq[wr + 16 + fr];
  const f32x4 yv = *(const f32x4*)&ysq[wc + kg * 4];

  float* outb = out + (size_t)b * Nn * Mm
              + (size_t)(bn * TN) * Mm + bm * TM;
  #pragma unroll
  for (int i = 0; i < 2; ++i) {
    const int n = wr + i * 16 + fr;
    float* orow = outb + (size_t)n * Mm;
    f32x4 ov;
    #pragma unroll
    for (int r = 0; r < 4; ++r) {
      float d2 = fmaf(-2.0f, acc[i][r], xv[i] + yv[r]);
      d2 = fmaxf(d2, 1e-7f);
      ov[r] = __builtin_amdgcn_rcpf(1.0f + __builtin_amdgcn_sqrtf(d2));
    }
    *(f32x4*)&orow[wc + kg * 4] = ov;
  }
}

extern "C" void kernel_launch(void* const* d_in, const int* in_sizes, int n_in,
                              void* d_out, int out_size, void* d_ws, size_t ws_size,
                              hipStream_t stream) {
  const float* X = (const float*)d_in[0];
  const float* Y = (const float*)d_in[1];
  float* out = (float*)d_out;
  dist_sim_kernel<<<dim3(NWG), dim3(256, 1, 1), 0, stream>>>(X, Y, out);
}

// Round 7
// 117.008 us; speedup vs baseline: 2.0980x; 2.0980x over previous
//
#include <hip/hip_runtime.h>
#include <hip/hip_bf16.h>

// X: [16, 2048, 128] f32, Y: [16, 2048, 128] f32 -> out: [16, 2048, 2048] f32
// out[b,n,m] = 1/(1+sqrt(max(||x||^2+||y||^2-2 x.y, 1e-7)))
#define Bb   16
#define Nn   2048
#define Mm   2048
#define Dd   128
#define TILE 128
#define NWG  (Bb * (Nn / TILE) * (Mm / TILE))   // 4096

typedef __attribute__((ext_vector_type(4))) float          f32x4;
typedef __attribute__((ext_vector_type(8))) unsigned short u16x8;
typedef __attribute__((ext_vector_type(8))) __bf16         bf16x8;

__device__ __forceinline__ unsigned short f32_to_bf16_rne(float f) {
  unsigned int u = __builtin_bit_cast(unsigned int, f);
  u += 0x7fffu + ((u >> 16) & 1u);
  return (unsigned short)(u >> 16);
}

// One block (512 thr, 8 waves) = one 128x128 tile; wave = 64x32 quadrant.
// Full-K staging: 65.5 KB LDS -> exactly 2 blocks/CU (the ONLY write-clean
// regime per R0-R6 counters), 16 waves/CU, and a SINGLE barrier between
// staging and MFMA (R5 had 3 barriers / 2 serialized stage rounds).
__global__ __launch_bounds__(512, 4)
void dist_sim_kernel(const float* __restrict__ X, const float* __restrict__ Y,
                     float* __restrict__ out) {
  __shared__ alignas(16) unsigned short Xs[TILE * Dd];  // 32 KB bf16, swizzled
  __shared__ alignas(16) unsigned short Ys[TILE * Dd];  // 32 KB
  __shared__ alignas(16) float xsq[TILE];
  __shared__ alignas(16) float ysq[TILE];

  const int tid = threadIdx.x;

  // Bijective XCD-chunked swizzle (NWG % 8 == 0), bm fastest.
  const int wg  = blockIdx.x;
  const int swz = (wg & 7) * (NWG / 8) + (wg >> 3);
  const int bm  = swz & 15;
  const int bn  = (swz >> 4) & 15;
  const int b   = swz >> 8;

  const float* Xb = X + ((size_t)b * Nn + (size_t)bn * TILE) * Dd;
  const float* Yb = Y + ((size_t)b * Mm + (size_t)bm * TILE) * Dd;

  // Staging map: 4 threads per 128-float row; thread covers 32 floats.
  const int row = tid >> 2;          // 0..127
  const int c0  = (tid & 3) * 32;    // 0,32,64,96

  // ---- stage BOTH tiles, full K, in one burst ------------------------------
  {
    const float* px = Xb + row * Dd + c0;
    const float* py = Yb + row * Dd + c0;
    f32x4 vx[8], vy[8];
    #pragma unroll
    for (int q = 0; q < 8; ++q) vx[q] = *(const f32x4*)(px + 4 * q);
    #pragma unroll
    for (int q = 0; q < 8; ++q) vy[q] = *(const f32x4*)(py + 4 * q);

    float sx = 0.f, sy = 0.f;
    #pragma unroll
    for (int q = 0; q < 4; ++q) {   // pairs -> u16x8 at col c0 + q*8
      u16x8 wx, wy;
      #pragma unroll
      for (int e = 0; e < 4; ++e) {
        const float x0 = vx[2 * q][e], x1 = vx[2 * q + 1][e];
        const float y0 = vy[2 * q][e], y1 = vy[2 * q + 1][e];
        sx += x0 * x0 + x1 * x1;
        sy += y0 * y0 + y1 * y1;
        wx[e] = f32_to_bf16_rne(x0); wx[e + 4] = f32_to_bf16_rne(x1);
        wy[e] = f32_to_bf16_rne(y0); wy[e + 4] = f32_to_bf16_rne(y1);
      }
      const int idx = (row * Dd + c0 + q * 8) ^ ((row & 7) << 3);  // swizzle
      *(u16x8*)&Xs[idx] = wx;
      *(u16x8*)&Ys[idx] = wy;
    }
    // 4 lanes share a row (consecutive lanes) -> fold norms, publish f32.
    sx += __shfl_xor(sx, 1); sy += __shfl_xor(sy, 1);
    sx += __shfl_xor(sx, 2); sy += __shfl_xor(sy, 2);
    if ((tid & 3) == 0) { xsq[row] = sx; ysq[row] = sy; }
  }

  const int lane = tid & 63;
  const int wid  = tid >> 6;           // 0..7
  const int wr   = (wid >> 2) * 64;    // 0 or 64
  const int wc   = (wid & 3) * 32;     // 0,32,64,96
  const int fr   = lane & 15;
  const int kg   = lane >> 4;          // 0..3

  f32x4 acc[4][2];
  #pragma unroll
  for (int i = 0; i < 4; ++i)
    #pragma unroll
    for (int j = 0; j < 2; ++j)
      acc[i][j] = (f32x4){0.f, 0.f, 0.f, 0.f};

  __syncthreads();  // the ONLY barrier

  // ---- MFMA: 4 k-steps, swapped operands: D[m-frag][n-frag] ----------------
  // acc[i][j] (lane fr,kg; reg r): n = wr+i*16+fr, m = wc+j*16+kg*4+r
  #pragma unroll
  for (int kk = 0; kk < 4; ++kk) {
    const int k0 = kk * 32 + kg * 8;
    bf16x8 a[4], bb[2];
    #pragma unroll
    for (int i = 0; i < 4; ++i) {
      const int r_ = wr + i * 16 + fr;
      const int idx = (r_ * Dd + k0) ^ ((r_ & 7) << 3);
      a[i] = __builtin_bit_cast(bf16x8, *(const u16x8*)&Xs[idx]);
    }
    #pragma unroll
    for (int j = 0; j < 2; ++j) {
      const int r_ = wc + j * 16 + fr;
      const int idx = (r_ * Dd + k0) ^ ((r_ & 7) << 3);
      bb[j] = __builtin_bit_cast(bf16x8, *(const u16x8*)&Ys[idx]);
    }
    #pragma unroll
    for (int i = 0; i < 4; ++i)
      #pragma unroll
      for (int j = 0; j < 2; ++j)
        acc[i][j] = __builtin_amdgcn_mfma_f32_16x16x32_bf16(bb[j], a[i], acc[i][j], 0, 0, 0);
  }

  // ---- epilogue: d2 -> 1/(1+sqrt(d2)); j=0,1 stores complete each 128B line
  float xv[4];
  #pragma unroll
  for (int i = 0; i < 4; ++i) xv[i] = xsq[wr + i * 16 + fr];
  f32x4 yv[2];
  #pragma unroll
  for (int j = 0; j < 2; ++j) yv[j] = *(const f32x4*)&ysq[wc + j * 16 + kg * 4];

  float* outb = out + (size_t)b * Nn * Mm
              + (size_t)(bn * TILE) * Mm + bm * TILE;
  #pragma unroll
  for (int i = 0; i < 4; ++i) {
    float* orow = outb + (size_t)(wr + i * 16 + fr) * Mm;
    #pragma unroll
    for (int j = 0; j < 2; ++j) {
      f32x4 ov;
      #pragma unroll
      for (int r = 0; r < 4; ++r) {
        float d2 = fmaf(-2.0f, acc[i][j][r], xv[i] + yv[j][r]);
        d2 = fmaxf(d2, 1e-7f);
        ov[r] = __builtin_amdgcn_rcpf(1.0f + __builtin_amdgcn_sqrtf(d2));
      }
      *(f32x4*)&orow[wc + j * 16 + kg * 4] = ov;
    }
  }
}

extern "C" void kernel_launch(void* const* d_in, const int* in_sizes, int n_in,
                              void* d_out, int out_size, void* d_ws, size_t ws_size,
                              hipStream_t stream) {
  const float* X = (const float*)d_in[0];
  const float* Y = (const float*)d_in[1];
  float* out = (float*)d_out;
  dist_sim_kernel<<<dim3(NWG), dim3(512, 1, 1), 0, stream>>>(X, Y, out);
}